// Round 4
// baseline (1554.478 us; speedup 1.0000x reference)
//
#include <hip/hip_runtime.h>

#define NN  50000
#define NE  600000
#define CC  128
#define NFF 256
#define ECH 64
#define EIN 192   // ECH + CC

typedef __attribute__((ext_vector_type(8))) short bf16x8;
typedef __attribute__((ext_vector_type(4))) short bf16x4;
typedef __attribute__((ext_vector_type(4))) float f32x4;

__device__ __forceinline__ float sspf(float v) {
    float sp = (v > 0.0f) ? (v + log1pf(__expf(-v))) : log1pf(__expf(v));
    return sp - 0.693147180559945f;
}
__device__ __forceinline__ short bf16r(float f) {
    unsigned u = __float_as_uint(f);
    u = (u + 0x7FFFu + ((u >> 16) & 1u)) >> 16;
    return (short)u;
}
__device__ __forceinline__ float bf2f(short s) {
    unsigned u = ((unsigned)(unsigned short)s) << 16;
    return __uint_as_float(u);
}

// ---- pack weights to bf16 fragment-linear layout for mfma_16x16x32 B-operand
__global__ void kpack(const float* __restrict__ Wf1, const float* __restrict__ Wf2,
                      const float* __restrict__ We, short* __restrict__ p) {
    int i = blockIdx.x * 256 + threadIdx.x;
    if (i < 16384) {                       // Wf1 [64][256]
        int j = i & 7, lane = (i >> 3) & 63, n16 = (i >> 9) & 15, ks = i >> 13;
        int k = ks * 32 + (lane >> 4) * 8 + j, col = n16 * 16 + (lane & 15);
        p[i] = bf16r(Wf1[k * NFF + col]);
    } else if (i < 16384 + 65536) {        // Wf2 [256][256]
        int t = i - 16384;
        int j = t & 7, lane = (t >> 3) & 63, n16 = (t >> 9) & 15, ks = t >> 13;
        int k = ks * 32 + (lane >> 4) * 8 + j, col = n16 * 16 + (lane & 15);
        p[i] = bf16r(Wf2[k * NFF + col]);
    } else if (i < 16384 + 65536 + 24576) { // We [192][128]
        int t = i - 81920;
        int j = t & 7, lane = (t >> 3) & 63, n16 = (t >> 9) & 7, ks = t >> 12;
        int k = ks * 32 + (lane >> 4) * 8 + j, col = n16 * 16 + (lane & 15);
        p[i] = bf16r(We[k * CC + col]);
    }
}

// ---- K0: zero a float4-multiple region ----
__global__ void k0_zero(float* __restrict__ p, long n4) {
    long i = (long)blockIdx.x * blockDim.x + threadIdx.x;
    long stride = (long)gridDim.x * blockDim.x;
    float4 z = {0.f, 0.f, 0.f, 0.f};
    for (; i < n4; i += stride) ((float4*)p)[i] = z;
}

// ---- counting sort by destination row ----
__global__ void k_cnt(const int* __restrict__ eidx, int* __restrict__ cnt) {
    int e = blockIdx.x * 256 + threadIdx.x;
    if (e < NE) atomicAdd(&cnt[eidx[e]], 1);
}

// single-block exclusive scan over cnt[NN] -> offw[NN]
__global__ __launch_bounds__(256) void k_scan(const int* __restrict__ cnt,
                                              int* __restrict__ offw) {
    __shared__ int sw[4];
    __shared__ int carry;
    int lane = threadIdx.x & 63, wv = threadIdx.x >> 6;
    if (threadIdx.x == 0) carry = 0;
    __syncthreads();
    for (int base = 0; base < NN; base += 256) {
        int i = base + (int)threadIdx.x;
        int v = (i < NN) ? cnt[i] : 0;
        int inc = v;
        #pragma unroll
        for (int d = 1; d < 64; d <<= 1) {
            int t = __shfl_up(inc, d, 64);
            if (lane >= d) inc += t;
        }
        if (lane == 63) sw[wv] = inc;
        __syncthreads();
        int woff = 0;
        #pragma unroll
        for (int k = 0; k < 4; ++k) woff += (k < wv) ? sw[k] : 0;
        if (i < NN) offw[i] = carry + woff + inc - v;
        int tot = sw[0] + sw[1] + sw[2] + sw[3];
        __syncthreads();
        if (threadIdx.x == 0) carry += tot;
        __syncthreads();
    }
}

__global__ void k_scatter(const int* __restrict__ eidx, int* __restrict__ offw,
                          int* __restrict__ perm) {
    int e = blockIdx.x * 256 + threadIdx.x;
    if (e < NE) {
        int pos = atomicAdd(&offw[eidx[e]], 1);
        perm[pos] = e;
    }
}

// ---- K1: h[N,NF] = x[N,C] @ W_lin1[C,NF], output bf16 ----
__global__ __launch_bounds__(256) void k1_h(const float* __restrict__ x,
                                            const float* __restrict__ W,
                                            short* __restrict__ h) {
    __shared__ __align__(16) float xs[16][CC];
    int n0 = blockIdx.x * 16;
    int tid = threadIdx.x;
    for (int i = tid; i < 16 * CC / 4; i += 256) {
        int nd = i >> 5;
        int c4 = i & 31;
        *(float4*)&xs[nd][c4 * 4] = ((const float4*)x)[(size_t)(n0 + nd) * 32 + c4];
    }
    __syncthreads();
    int j0 = (tid & 63) * 4;
    int i0 = (tid >> 6) * 4;
    float acc[4][4] = {};
    #pragma unroll 4
    for (int k = 0; k < CC; ++k) {
        float4 b = *(const float4*)&W[k * NFF + j0];
        #pragma unroll
        for (int i = 0; i < 4; ++i) {
            float a = xs[i0 + i][k];
            acc[i][0] = fmaf(a, b.x, acc[i][0]);
            acc[i][1] = fmaf(a, b.y, acc[i][1]);
            acc[i][2] = fmaf(a, b.z, acc[i][2]);
            acc[i][3] = fmaf(a, b.w, acc[i][3]);
        }
    }
    #pragma unroll
    for (int i = 0; i < 4; ++i) {
        bf16x4 v = {bf16r(acc[i][0]), bf16r(acc[i][1]), bf16r(acc[i][2]), bf16r(acc[i][3])};
        *(bf16x4*)&h[(size_t)(n0 + i0 + i) * NFF + j0] = v;
    }
}

// ---- K2: MFMA fused filter-net + gather + modulate + scatter-add, SORTED edges ----
// block = 256 thr (4 waves), 32 sorted edges; wave w owns cols [w*64, w*64+64)
__global__ __launch_bounds__(256, 6) void k2_mfma(
        const float* __restrict__ ea, const int* __restrict__ eidx,
        const int* __restrict__ perm,
        const short* __restrict__ pWf1, const float* __restrict__ bf1v,
        const short* __restrict__ pWf2, const float* __restrict__ bf2v,
        const short* __restrict__ h, float* __restrict__ agg) {
    __shared__ char eaS[32 * 128];   // [32][64] bf16, stride 128B, XOR-swizzled
    __shared__ char t1S[32 * 512];   // [32][256] bf16, stride 512B, XOR-swizzled
    __shared__ int rowS[32], colS[32];
    int e0 = blockIdx.x * 32;
    int tid = threadIdx.x;
    int lane = tid & 63, w = tid >> 6;
    int q = lane >> 4, l15 = lane & 15;

    if (tid < 32) {
        int p = perm[e0 + tid];
        rowS[tid] = eidx[p];
        colS[tid] = eidx[NE + p];
    }

    {   // stage ea[perm] -> bf16 swizzled LDS: thread t: row=t>>3, 8 cols at (t&7)*8
        int r = tid >> 3, cp = tid & 7;
        int p = perm[e0 + r];
        const float4* src = (const float4*)(ea + (size_t)p * ECH + cp * 8);
        float4 f0 = src[0], f1 = src[1];
        bf16x8 c0 = {bf16r(f0.x), bf16r(f0.y), bf16r(f0.z), bf16r(f0.w),
                     bf16r(f1.x), bf16r(f1.y), bf16r(f1.z), bf16r(f1.w)};
        int sw = (r & 7) << 4;
        *(bf16x8*)(eaS + r * 128 + ((cp * 16) ^ sw)) = c0;
    }
    __syncthreads();

    f32x4 acc[2][4];
    #pragma unroll
    for (int mf = 0; mf < 2; ++mf)
        #pragma unroll
        for (int nf = 0; nf < 4; ++nf) acc[mf][nf] = f32x4{0.f, 0.f, 0.f, 0.f};

    // phase 1: t1 = ssp(ea @ Wf1 + b1), K=64, M=32
    #pragma unroll
    for (int ks = 0; ks < 2; ++ks) {
        bf16x8 a[2];
        #pragma unroll
        for (int mf = 0; mf < 2; ++mf) {
            int row = mf * 16 + l15;
            a[mf] = *(const bf16x8*)(eaS + row * 128 + ((ks * 64 + q * 16) ^ ((row & 7) << 4)));
        }
        #pragma unroll
        for (int nf = 0; nf < 4; ++nf) {
            bf16x8 b = *(const bf16x8*)(pWf1 + (((ks * 16 + w * 4 + nf) * 64) + lane) * 8);
            #pragma unroll
            for (int mf = 0; mf < 2; ++mf)
                acc[mf][nf] = __builtin_amdgcn_mfma_f32_16x16x32_bf16(a[mf], b, acc[mf][nf], 0, 0, 0);
        }
    }
    // ssp + bias, write t1 (bf16, swizzled). C/D: col=lane&15, row=(lane>>4)*4+r
    #pragma unroll
    for (int nf = 0; nf < 4; ++nf) {
        int col = w * 64 + nf * 16 + l15;
        float bias = bf1v[col];
        #pragma unroll
        for (int mf = 0; mf < 2; ++mf) {
            #pragma unroll
            for (int r = 0; r < 4; ++r) {
                int row = mf * 16 + q * 4 + r;
                *(short*)(t1S + row * 512 + ((col * 2) ^ ((row & 7) << 4))) =
                    bf16r(sspf(acc[mf][nf][r] + bias));
            }
        }
    }
    __syncthreads();

    #pragma unroll
    for (int mf = 0; mf < 2; ++mf)
        #pragma unroll
        for (int nf = 0; nf < 4; ++nf) acc[mf][nf] = f32x4{0.f, 0.f, 0.f, 0.f};

    // phase 2: Wf = t1 @ Wf2 + b2, K=256, M=32
    for (int ks = 0; ks < 8; ++ks) {
        bf16x8 a[2];
        #pragma unroll
        for (int mf = 0; mf < 2; ++mf) {
            int row = mf * 16 + l15;
            a[mf] = *(const bf16x8*)(t1S + row * 512 + ((ks * 64 + q * 16) ^ ((row & 7) << 4)));
        }
        #pragma unroll
        for (int nf = 0; nf < 4; ++nf) {
            bf16x8 b = *(const bf16x8*)(pWf2 + (((ks * 16 + w * 4 + nf) * 64) + lane) * 8);
            #pragma unroll
            for (int mf = 0; mf < 2; ++mf)
                acc[mf][nf] = __builtin_amdgcn_mfma_f32_16x16x32_bf16(a[mf], b, acc[mf][nf], 0, 0, 0);
        }
    }

    // epilogue: gather h[col] (bf16), modulate, run-length-merged scatter-add.
    // edges eloc = mf*16 + q*4 + r: for fixed (mf,q) the 4 r are CONSECUTIVE
    // sorted edges -> usually same row -> merge before atomic.
    #pragma unroll
    for (int nf = 0; nf < 4; ++nf) {
        int col = w * 64 + nf * 16 + l15;
        float bias = bf2v[col];
        #pragma unroll
        for (int mf = 0; mf < 2; ++mf) {
            int ebase = mf * 16 + q * 4;
            float sum = 0.f;
            int prow = rowS[ebase];
            #pragma unroll
            for (int r = 0; r < 4; ++r) {
                int eloc = ebase + r;
                float wf = acc[mf][nf][r] + bias;
                float hv = bf2f(h[(size_t)colS[eloc] * NFF + col]);
                int rw = rowS[eloc];
                if (rw != prow) {
                    atomicAdd(&agg[(size_t)prow * NFF + col], sum);
                    sum = 0.f;
                    prow = rw;
                }
                sum = fmaf(hv, wf, sum);
            }
            atomicAdd(&agg[(size_t)prow * NFF + col], sum);
        }
    }
}

// ---- K3: x_out = relu(ssp(agg@Wl2+b2)@Wl3+b3) + x ----
__global__ __launch_bounds__(128) void k3_node(
        const float* __restrict__ agg,
        const float* __restrict__ Wl2, const float* __restrict__ bl2,
        const float* __restrict__ Wl3, const float* __restrict__ bl3,
        const float* __restrict__ x, float* __restrict__ xo) {
    __shared__ __align__(16) float as[16][NFF];
    __shared__ __align__(16) float t2[16][CC];
    int n0 = blockIdx.x * 16;
    int tid = threadIdx.x;
    for (int i = tid; i < 16 * NFF / 4; i += 128) {
        int nd = i >> 6;
        int c4 = i & 63;
        *(float4*)&as[nd][c4 * 4] = ((const float4*)agg)[(size_t)(n0 + nd) * 64 + c4];
    }
    __syncthreads();
    int j0 = (tid & 31) * 4;
    int i0 = (tid >> 5) * 4;

    float acc[4][4] = {};
    #pragma unroll 4
    for (int k = 0; k < NFF; ++k) {
        float4 b = *(const float4*)&Wl2[k * CC + j0];
        #pragma unroll
        for (int i = 0; i < 4; ++i) {
            float a = as[i0 + i][k];
            acc[i][0] = fmaf(a, b.x, acc[i][0]);
            acc[i][1] = fmaf(a, b.y, acc[i][1]);
            acc[i][2] = fmaf(a, b.z, acc[i][2]);
            acc[i][3] = fmaf(a, b.w, acc[i][3]);
        }
    }
    float4 b2v = *(const float4*)&bl2[j0];
    #pragma unroll
    for (int i = 0; i < 4; ++i) {
        float4 v;
        v.x = sspf(acc[i][0] + b2v.x);
        v.y = sspf(acc[i][1] + b2v.y);
        v.z = sspf(acc[i][2] + b2v.z);
        v.w = sspf(acc[i][3] + b2v.w);
        *(float4*)&t2[i0 + i][j0] = v;
    }
    __syncthreads();

    float acc3[4][4] = {};
    #pragma unroll 4
    for (int k = 0; k < CC; ++k) {
        float4 b = *(const float4*)&Wl3[k * CC + j0];
        #pragma unroll
        for (int i = 0; i < 4; ++i) {
            float a = t2[i0 + i][k];
            acc3[i][0] = fmaf(a, b.x, acc3[i][0]);
            acc3[i][1] = fmaf(a, b.y, acc3[i][1]);
            acc3[i][2] = fmaf(a, b.z, acc3[i][2]);
            acc3[i][3] = fmaf(a, b.w, acc3[i][3]);
        }
    }
    float4 b3v = *(const float4*)&bl3[j0];
    #pragma unroll
    for (int i = 0; i < 4; ++i) {
        size_t base = (size_t)(n0 + i0 + i) * CC + j0;
        float4 xv = *(const float4*)&x[base];
        float4 v;
        v.x = fmaxf(acc3[i][0] + b3v.x, 0.f) + xv.x;
        v.y = fmaxf(acc3[i][1] + b3v.y, 0.f) + xv.y;
        v.z = fmaxf(acc3[i][2] + b3v.z, 0.f) + xv.z;
        v.w = fmaxf(acc3[i][3] + b3v.w, 0.f) + xv.w;
        *(float4*)&xo[base] = v;
    }
}

// ---- K4: MFMA e_out = tanh([ea | xo[row]+xo[col]] @ We + be), K=192, N=128 ----
__global__ __launch_bounds__(256) void k4_mfma(
        const float* __restrict__ ea, const int* __restrict__ eidx,
        const float* __restrict__ xo, const short* __restrict__ pWe,
        const float* __restrict__ bev, float* __restrict__ eo) {
    __shared__ char aS[64 * 384];    // [64][192] bf16, stride 384B, XOR-swizzled
    int e0 = blockIdx.x * 64;
    int tid = threadIdx.x;
    int lane = tid & 63, w = tid >> 6;
    int q = lane >> 4, l15 = lane & 15;

    {   // stage ea (k 0..63)
        int r = tid >> 2, cp = tid & 3;
        const float4* src = (const float4*)(ea + (size_t)(e0 + r) * ECH + cp * 16);
        float4 f0 = src[0], f1 = src[1], f2 = src[2], f3 = src[3];
        bf16x8 c0 = {bf16r(f0.x), bf16r(f0.y), bf16r(f0.z), bf16r(f0.w),
                     bf16r(f1.x), bf16r(f1.y), bf16r(f1.z), bf16r(f1.w)};
        bf16x8 c1 = {bf16r(f2.x), bf16r(f2.y), bf16r(f2.z), bf16r(f2.w),
                     bf16r(f3.x), bf16r(f3.y), bf16r(f3.z), bf16r(f3.w)};
        int sw = (r & 7) << 4;
        *(bf16x8*)(aS + r * 384 + ((cp * 32) ^ sw)) = c0;
        *(bf16x8*)(aS + r * 384 + ((cp * 32 + 16) ^ sw)) = c1;
    }
    {   // stage xo[row]+xo[col] (k 64..191)
        int e = tid >> 2, p = tid & 3;
        int rr = eidx[e0 + e], cc = eidx[NE + e0 + e];
        const float4* xr = (const float4*)(xo + (size_t)rr * CC);
        const float4* xc = (const float4*)(xo + (size_t)cc * CC);
        int sw = (e & 7) << 4;
        #pragma unroll
        for (int it = 0; it < 8; ++it) {
            int fi = p + it * 4;
            float4 va = xr[fi], vb = xc[fi];
            bf16x4 hv = {bf16r(va.x + vb.x), bf16r(va.y + vb.y),
                         bf16r(va.z + vb.z), bf16r(va.w + vb.w)};
            int byte = (ECH + fi * 4) * 2;
            *(bf16x4*)(aS + e * 384 + (byte ^ sw)) = hv;
        }
    }
    __syncthreads();

    f32x4 acc[8];
    #pragma unroll
    for (int nf = 0; nf < 8; ++nf) acc[nf] = f32x4{0.f, 0.f, 0.f, 0.f};

    #pragma unroll
    for (int ks = 0; ks < 6; ++ks) {
        int row = w * 16 + l15;
        bf16x8 a = *(const bf16x8*)(aS + row * 384 + ((ks * 64 + q * 16) ^ ((row & 7) << 4)));
        #pragma unroll
        for (int nf = 0; nf < 8; ++nf) {
            bf16x8 b = *(const bf16x8*)(pWe + (((ks * 8 + nf) * 64) + lane) * 8);
            acc[nf] = __builtin_amdgcn_mfma_f32_16x16x32_bf16(a, b, acc[nf], 0, 0, 0);
        }
    }
    #pragma unroll
    for (int nf = 0; nf < 8; ++nf) {
        int col = nf * 16 + l15;
        float bias = bev[col];
        #pragma unroll
        for (int r = 0; r < 4; ++r) {
            int e = e0 + w * 16 + q * 4 + r;
            eo[(size_t)e * CC + col] = tanhf(acc[nf][r] + bias);
        }
    }
}

extern "C" void kernel_launch(void* const* d_in, const int* in_sizes, int n_in,
                              void* d_out, int out_size, void* d_ws, size_t ws_size,
                              hipStream_t stream) {
    const float* x   = (const float*)d_in[0];
    const int*   ei  = (const int*)d_in[1];
    const float* ea  = (const float*)d_in[2];
    const float* Wf1 = (const float*)d_in[4];
    const float* bf1 = (const float*)d_in[5];
    const float* Wf2 = (const float*)d_in[6];
    const float* bf2 = (const float*)d_in[7];
    const float* Wl1 = (const float*)d_in[8];
    const float* Wl2 = (const float*)d_in[9];
    const float* bl2 = (const float*)d_in[10];
    const float* Wl3 = (const float*)d_in[11];
    const float* bl3 = (const float*)d_in[12];
    const float* We  = (const float*)d_in[13];
    const float* be  = (const float*)d_in[14];

    float* xo = (float*)d_out;                 // [N, C]
    float* eo = xo + (size_t)NN * CC;          // [E, C]

    // ws: [packed weights][agg fp32 51.2MB]
    short* pW   = (short*)d_ws;
    short* pWf1 = pW;
    short* pWf2 = pW + 16384;
    short* pWe  = pW + 81920;
    float* agg  = (float*)((char*)d_ws + 262144);
    size_t one  = (size_t)NN * NFF;

    // scratch carved from the TAIL of the e_out region (written only by K4 at
    // the very end): h bf16 [N,NF], perm [E], cnt/offw [N]. All 256B-aligned.
    char* top  = (char*)d_out + (size_t)out_size * sizeof(float);
    short* h   = (short*)(top - 25600000);              // NN*NFF*2
    int* perm  = (int*)((char*)h - 2400000);            // NE*4
    int* cnt   = (int*)((char*)perm - 200704);
    int* offw  = (int*)((char*)cnt - 200704);

    kpack<<<416, 256, 0, stream>>>(Wf1, Wf2, We, pW);
    k0_zero<<<1024, 256, 0, stream>>>(agg, (long)(one / 4));
    k0_zero<<<49, 256, 0, stream>>>((float*)cnt, 12500);
    k_cnt<<<(NE + 255) / 256, 256, 0, stream>>>(ei, cnt);
    k_scan<<<1, 256, 0, stream>>>(cnt, offw);
    k_scatter<<<(NE + 255) / 256, 256, 0, stream>>>(ei, offw, perm);
    k1_h<<<NN / 16, 256, 0, stream>>>(x, Wl1, h);
    k2_mfma<<<NE / 32, 256, 0, stream>>>(ea, ei, perm, pWf1, bf1, pWf2, bf2, h, agg);
    k3_node<<<NN / 16, 128, 0, stream>>>(agg, Wl2, bl2, Wl3, bl3, x, xo);
    k4_mfma<<<NE / 64, 256, 0, stream>>>(ea, ei, xo, pWe, be, eo);
}